// Round 12
// baseline (299.101 us; speedup 1.0000x reference)
//
#include <hip/hip_runtime.h>

#define N_NODES 50000
#define NPAD 50048            // padded row count (multiple of 128)
#define FEAT 256
#define HID 64
#define NEDGE 800000
#define SCAN_CHUNK 2048
#define NB_SCAN 25            // ceil(50000/2048)
#define NB_EDGE 3125          // NEDGE/256
#define NB_GEMM 391           // NPAD/128

typedef unsigned short bf16_t;
typedef unsigned char fp8_t;
typedef long long i64;
typedef __attribute__((ext_vector_type(8))) short bf16x8;   // 8 bf16 = 4 VGPR
typedef __attribute__((ext_vector_type(4))) float f32x4;

#define MFMA_BF16 __builtin_amdgcn_mfma_f32_16x16x32_bf16
#define MFMA_FP8  __builtin_amdgcn_mfma_f32_16x16x32_fp8_fp8

__device__ __forceinline__ bf16_t f2bf(float f) {
    union { float f; unsigned u; } v; v.f = f;
    unsigned r = v.u + 0x7fff + ((v.u >> 16) & 1);   // RNE
    return (bf16_t)(r >> 16);
}
__device__ __forceinline__ unsigned pack2(float lo, float hi) {
    return ((unsigned)f2bf(lo)) | (((unsigned)f2bf(hi)) << 16);
}

// ---- manual OCP e4m3fn (bit-exact encode; HW-MFMA-compatible) ----
// encode: RNE, saturate to +-448, flush |x|<2^-6 to 0 (no subnormals stored)
__device__ __forceinline__ unsigned f2e4m3(float f) {
    union { float f; unsigned u; } v; v.f = f;
    unsigned s = (v.u >> 24) & 0x80u;
    unsigned au = v.u & 0x7fffffffu;
    if (au >= 0x43e80000u) return s | 0x7eu;      // |x| >= 464 -> 448
    if (au <  0x3c800000u) return s;              // |x| < 2^-6 -> 0
    unsigned t = au - (120u << 23);
    t = t + 0x7ffffu + ((t >> 20) & 1u);          // RNE at dropped bit 20
    unsigned w = t >> 20;
    if (w > 0x7eu) w = 0x7eu;
    return s | w;
}
__device__ __forceinline__ float e4m3f(unsigned b) {
    unsigned em = b & 0x7fu;
    unsigned s = (b & 0x80u) << 24;
    union { unsigned u; float f; } v;
    if ((em >> 3) == 0) { v.u = s; return v.f; }
    v.u = s | ((em << 20) + (120u << 23));
    return v.f;
}

// ---------------- fused prep: hist ∥ pack_we(bf16) ∥ pack_wc(fp8, scale-folded) ----------------
__device__ __forceinline__ void pack_we_body(const float* __restrict__ wsrc,
        bf16_t* __restrict__ wdst, int idx) {
    int lane = idx & 63, nt = (idx >> 6) & 3, ks = idx >> 8;
    int kb  = ks * 32 + ((lane >> 4) * 8);
    int col = nt * 16 + (lane & 15);
    unsigned p[4];
#pragma unroll
    for (int j = 0; j < 4; ++j)
        p[j] = pack2(wsrc[(size_t)(kb + 2*j) * 64 + col],
                     wsrc[(size_t)(kb + 2*j + 1) * 64 + col]);
    uint4 u; u.x = p[0]; u.y = p[1]; u.z = p[2]; u.w = p[3];
    *(uint4*)(wdst + (size_t)idx * 8) = u;
}

// fp8 pack of Wc with activation-scale compensation: k<64 ->x1, k<192 ->x2, else x8
__device__ __forceinline__ void pack_wc8_body(const float* __restrict__ wsrc,
        fp8_t* __restrict__ wdst, int idx) {
    int lane = idx & 63, nt = (idx >> 6) & 3, ks = idx >> 8;
    int kb  = ks * 32 + ((lane >> 4) * 8);
    int col = nt * 16 + (lane & 15);
    float scale = (kb < 64) ? 1.f : (kb < 192) ? 2.f : 8.f;  // 8-group never straddles
    unsigned long long u = 0;
#pragma unroll
    for (int j = 0; j < 8; ++j)
        u |= ((unsigned long long)f2e4m3(wsrc[(size_t)(kb + j) * 64 + col] * scale)) << (8*j);
    *(unsigned long long*)(wdst + (size_t)idx * 8) = u;
}

__global__ __launch_bounds__(256) void prep_kernel(const int* __restrict__ rows,
        int* __restrict__ cnt, const float* __restrict__ we, bf16_t* __restrict__ wep,
        const float* __restrict__ wc, fp8_t* __restrict__ wcp) {
    const int b = blockIdx.x, t = threadIdx.x;
    if (b < NB_EDGE) {
        int e = b * 256 + t;
        if (e < NEDGE) atomicAdd(&cnt[rows[e]], 1);
    } else if (b < NB_EDGE + 8) {
        pack_we_body(we, wep, (b - NB_EDGE) * 256 + t);
    } else {
        pack_wc8_body(wc, wcp, (b - NB_EDGE - 8) * 256 + t);
    }
}

// ---------------- scans ----------------
__global__ __launch_bounds__(256) void scan_a(const int* __restrict__ cnt,
        int* __restrict__ bsum) {
    __shared__ int sd[256];
    const int t = threadIdx.x;
    const int base = blockIdx.x * SCAN_CHUNK + t * 8;
    int s = 0;
#pragma unroll
    for (int i = 0; i < 8; ++i) {
        int idx = base + i;
        s += (idx < N_NODES) ? cnt[idx] : 0;
    }
    sd[t] = s; __syncthreads();
    for (int off = 128; off > 0; off >>= 1) {
        if (t < off) sd[t] += sd[t + off];
        __syncthreads();
    }
    if (t == 0) bsum[blockIdx.x] = sd[0];
}

__global__ __launch_bounds__(256) void scan_c(const int* __restrict__ cnt,
        const int* __restrict__ bsum, int* __restrict__ rowPtr,
        int* __restrict__ fill) {
    __shared__ int sd[256];
    __shared__ int sboff;
    const int t = threadIdx.x;
    const int base = blockIdx.x * SCAN_CHUNK + t * 8;
    if (t == 0) {
        int a = 0, tot = 0;
        for (int b = 0; b < NB_SCAN; ++b) {
            int v = bsum[b];
            if (b < (int)blockIdx.x) a += v;
            tot += v;
        }
        sboff = a;
        if (blockIdx.x == NB_SCAN - 1) rowPtr[N_NODES] = tot;
    }
    int v[8];
    int s = 0;
#pragma unroll
    for (int i = 0; i < 8; ++i) {
        int idx = base + i;
        v[i] = (idx < N_NODES) ? cnt[idx] : 0;
        s += v[i];
    }
    sd[t] = s; __syncthreads();
    for (int off = 1; off < 256; off <<= 1) {
        int add = (t >= off) ? sd[t - off] : 0;
        __syncthreads();
        sd[t] += add;
        __syncthreads();
    }
    int run = sboff + (sd[t] - s);
#pragma unroll
    for (int i = 0; i < 8; ++i) {
        int idx = base + i;
        if (idx < N_NODES) { rowPtr[idx] = run; fill[idx] = 0; }
        run += v[i];
    }
}

// ---------------- fused scatter ∥ embed_mfma (r0 stored fp8) ----------------
__global__ __launch_bounds__(256) void scatter_embed_kernel(
        const int* __restrict__ rows, const int* __restrict__ cols,
        const float* __restrict__ vals, const int* __restrict__ rowPtr,
        int* __restrict__ fill, uint2* __restrict__ colval,
        const float* __restrict__ x, const bf16_t* __restrict__ wep,
        fp8_t* __restrict__ r0) {
    if (blockIdx.x < NB_EDGE) {
        int e = blockIdx.x * 256 + threadIdx.x;
        if (e < NEDGE) {
            int r = rows[e];
            int p = rowPtr[r] + atomicAdd(&fill[r], 1);
            uint2 cv; cv.x = (unsigned)cols[e]; cv.y = __float_as_uint(vals[e]);
            colval[p] = cv;
        }
        return;
    }
    const int blk = blockIdx.x - NB_EDGE;
    const int t = threadIdx.x;
    const int l = t & 63, w = t >> 6;
    const int lm = l & 15, lg = l >> 4;
    const int base = blk * 128 + w * 32;

    int m0 = base + lm, m1 = base + 16 + lm;
    if (m0 >= N_NODES) m0 = N_NODES - 1;
    if (m1 >= N_NODES) m1 = N_NODES - 1;
    const float* xp0 = x + (size_t)m0 * FEAT + lg * 8;
    const float* xp1 = x + (size_t)m1 * FEAT + lg * 8;

    f32x4 acc[2][4];
#pragma unroll
    for (int i = 0; i < 2; ++i)
#pragma unroll
        for (int j = 0; j < 4; ++j) acc[i][j] = (f32x4){0.f, 0.f, 0.f, 0.f};

    auto aload = [&](const float* p) {
        float4 u0 = *(const float4*)(p);
        float4 u1 = *(const float4*)(p + 4);
        bf16x8 r;
        r[0] = (short)f2bf(u0.x); r[1] = (short)f2bf(u0.y);
        r[2] = (short)f2bf(u0.z); r[3] = (short)f2bf(u0.w);
        r[4] = (short)f2bf(u1.x); r[5] = (short)f2bf(u1.y);
        r[6] = (short)f2bf(u1.z); r[7] = (short)f2bf(u1.w);
        return r;
    };
    auto wb = [&](int ks, int nt) {
        return *(const bf16x8*)(wep + ((size_t)(ks * 4 + nt) * 64 + l) * 8);
    };

    const int NK = FEAT / 32;  // 8
    bf16x8 a0 = aload(xp0), a1 = aload(xp1);
    bf16x8 b0 = wb(0,0), b1 = wb(0,1), b2 = wb(0,2), b3 = wb(0,3);
    for (int ks = 0; ks < NK; ++ks) {
        bf16x8 na0, na1, nb0, nb1, nb2, nb3;
        const bool more = (ks + 1 < NK);
        if (more) {
            int kt = (ks + 1) * 32;
            na0 = aload(xp0 + kt); na1 = aload(xp1 + kt);
            nb0 = wb(ks+1,0); nb1 = wb(ks+1,1); nb2 = wb(ks+1,2); nb3 = wb(ks+1,3);
        }
        acc[0][0] = MFMA_BF16(a0, b0, acc[0][0], 0, 0, 0);
        acc[1][0] = MFMA_BF16(a1, b0, acc[1][0], 0, 0, 0);
        acc[0][1] = MFMA_BF16(a0, b1, acc[0][1], 0, 0, 0);
        acc[1][1] = MFMA_BF16(a1, b1, acc[1][1], 0, 0, 0);
        acc[0][2] = MFMA_BF16(a0, b2, acc[0][2], 0, 0, 0);
        acc[1][2] = MFMA_BF16(a1, b2, acc[1][2], 0, 0, 0);
        acc[0][3] = MFMA_BF16(a0, b3, acc[0][3], 0, 0, 0);
        acc[1][3] = MFMA_BF16(a1, b3, acc[1][3], 0, 0, 0);
        if (more) { a0 = na0; a1 = na1; b0 = nb0; b1 = nb1; b2 = nb2; b3 = nb3; }
    }

#pragma unroll
    for (int rt = 0; rt < 2; ++rt)
#pragma unroll
        for (int r = 0; r < 4; ++r) {
            int R = base + rt * 16 + lg * 4 + r;
            if (R < N_NODES) {
                fp8_t* o = r0 + (size_t)R * HID + lm;
                o[0]  = (fp8_t)f2e4m3(fmaxf(acc[rt][0][r], 0.f));
                o[16] = (fp8_t)f2e4m3(fmaxf(acc[rt][1][r], 0.f));
                o[32] = (fp8_t)f2e4m3(fmaxf(acc[rt][2][r], 0.f));
                o[48] = (fp8_t)f2e4m3(fmaxf(acc[rt][3][r], 0.f));
            }
        }
}

// ---------------- SpMM (CSR, wave/row, fp8 storage, fp32 accum) ----------------
__global__ __launch_bounds__(256) void spmm64_kernel(const uint2* __restrict__ colval,
        const int* __restrict__ rowPtr,
        const fp8_t* __restrict__ src, fp8_t* __restrict__ dst) {
    const int lane = threadIdx.x & 63;
    const int row  = (int)((blockIdx.x * 256u + threadIdx.x) >> 6);
    const int beg = rowPtr[row], end = rowPtr[row + 1];
    float acc = 0.f;
    int i = beg;
    for (; i + 8 <= end; i += 8) {
        uint2 cv[8]; float g[8];
#pragma unroll
        for (int j = 0; j < 8; ++j) cv[j] = colval[i+j];
#pragma unroll
        for (int j = 0; j < 8; ++j) g[j] = e4m3f(src[(size_t)cv[j].x*HID + lane]);
#pragma unroll
        for (int j = 0; j < 8; ++j) acc += __uint_as_float(cv[j].y)*g[j];
    }
    for (; i < end; ++i) {
        uint2 cv = colval[i];
        acc += __uint_as_float(cv.y) * e4m3f(src[(size_t)cv.x*HID + lane]);
    }
    dst[(size_t)row*HID + lane] = (fp8_t)f2e4m3(acc);
}

// t = adj@s fused with r1cat = relu(concat[s-r0, t-s-r0]); stored x0.5
__global__ __launch_bounds__(256) void spmm64f_kernel(const uint2* __restrict__ colval,
        const int* __restrict__ rowPtr,
        const fp8_t* __restrict__ s, const fp8_t* __restrict__ r0,
        fp8_t* __restrict__ r1c) {
    const int lane = threadIdx.x & 63;
    const int row  = (int)((blockIdx.x * 256u + threadIdx.x) >> 6);
    const int beg = rowPtr[row], end = rowPtr[row + 1];
    float acc = 0.f;
    int i = beg;
    for (; i + 8 <= end; i += 8) {
        uint2 cv[8]; float g[8];
#pragma unroll
        for (int j = 0; j < 8; ++j) cv[j] = colval[i+j];
#pragma unroll
        for (int j = 0; j < 8; ++j) g[j] = e4m3f(s[(size_t)cv[j].x*HID + lane]);
#pragma unroll
        for (int j = 0; j < 8; ++j) acc += __uint_as_float(cv[j].y)*g[j];
    }
    for (; i < end; ++i) {
        uint2 cv = colval[i];
        acc += __uint_as_float(cv.y) * e4m3f(s[(size_t)cv.x*HID + lane]);
    }
    float sv = e4m3f(s[(size_t)row*HID + lane]);
    float rv = e4m3f(r0[(size_t)row*HID + lane]);
    r1c[(size_t)row*128 + lane]      = (fp8_t)f2e4m3(0.5f * fmaxf(sv - rv, 0.f));
    r1c[(size_t)row*128 + 64 + lane] = (fp8_t)f2e4m3(0.5f * fmaxf(acc - sv - rv, 0.f));
}

// s2' = adj @ r1c_stored  (inherits the x0.5 scale exactly)
__global__ __launch_bounds__(256) void spmm128_kernel(const uint2* __restrict__ colval,
        const int* __restrict__ rowPtr,
        const fp8_t* __restrict__ src, fp8_t* __restrict__ dst) {
    const int lane = threadIdx.x & 63;
    const int row  = (int)((blockIdx.x * 256u + threadIdx.x) >> 6);
    const int beg = rowPtr[row], end = rowPtr[row + 1];
    const unsigned short* srcu = (const unsigned short*)src;  // row stride 64 ushorts
    float a0 = 0.f, a1 = 0.f;
    int i = beg;
    for (; i + 4 <= end; i += 4) {
        uint2 cv[4]; unsigned short u[4];
#pragma unroll
        for (int j = 0; j < 4; ++j) cv[j] = colval[i+j];
#pragma unroll
        for (int j = 0; j < 4; ++j) u[j] = srcu[(size_t)cv[j].x*64 + lane];
#pragma unroll
        for (int j = 0; j < 4; ++j) {
            float lo = e4m3f(u[j] & 0xff), hi = e4m3f(u[j] >> 8);
            float v = __uint_as_float(cv[j].y);
            a0 += v*lo; a1 += v*hi;
        }
    }
    for (; i < end; ++i) {
        uint2 cv = colval[i];
        unsigned short u = srcu[(size_t)cv.x*64 + lane];
        float lo = e4m3f(u & 0xff), hi = e4m3f(u >> 8);
        float v = __uint_as_float(cv.y);
        a0 += v*lo; a1 += v*hi;
    }
    ((unsigned short*)dst)[(size_t)row*64 + lane] =
        (unsigned short)(f2e4m3(a0) | (f2e4m3(a1) << 8));
}

// t2' = adj@s2'; r2c = relu([s2-r1, t2-s2-r1]) stored x1/8  (primed = x0.5 domain)
__global__ __launch_bounds__(256) void spmm128f_kernel(const uint2* __restrict__ colval,
        const int* __restrict__ rowPtr,
        const fp8_t* __restrict__ s2, const fp8_t* __restrict__ r1,
        fp8_t* __restrict__ r2c) {
    const int lane = threadIdx.x & 63;
    const int row  = (int)((blockIdx.x * 256u + threadIdx.x) >> 6);
    const int beg = rowPtr[row], end = rowPtr[row + 1];
    const unsigned short* s2u = (const unsigned short*)s2;
    const unsigned short* r1u = (const unsigned short*)r1;
    float a0 = 0.f, a1 = 0.f;
    int i = beg;
    for (; i + 4 <= end; i += 4) {
        uint2 cv[4]; unsigned short u[4];
#pragma unroll
        for (int j = 0; j < 4; ++j) cv[j] = colval[i+j];
#pragma unroll
        for (int j = 0; j < 4; ++j) u[j] = s2u[(size_t)cv[j].x*64 + lane];
#pragma unroll
        for (int j = 0; j < 4; ++j) {
            float lo = e4m3f(u[j] & 0xff), hi = e4m3f(u[j] >> 8);
            float v = __uint_as_float(cv[j].y);
            a0 += v*lo; a1 += v*hi;
        }
    }
    for (; i < end; ++i) {
        uint2 cv = colval[i];
        unsigned short u = s2u[(size_t)cv.x*64 + lane];
        float lo = e4m3f(u & 0xff), hi = e4m3f(u >> 8);
        float v = __uint_as_float(cv.y);
        a0 += v*lo; a1 += v*hi;
    }
    unsigned short us = s2u[(size_t)row*64 + lane];
    unsigned short ur = r1u[(size_t)row*64 + lane];
    float s0v = e4m3f(us & 0xff), s1v = e4m3f(us >> 8);
    float r0v = e4m3f(ur & 0xff), r1v = e4m3f(ur >> 8);
    // true r2c = 2*relu(primed diffs); store /8 -> 0.25*
    unsigned short* r2u = (unsigned short*)r2c;  // row stride 128 ushorts
    r2u[(size_t)row*128 + lane] = (unsigned short)(
        f2e4m3(0.25f * fmaxf(s0v - r0v, 0.f)) |
        (f2e4m3(0.25f * fmaxf(s1v - r1v, 0.f)) << 8));
    r2u[(size_t)row*128 + 64 + lane] = (unsigned short)(
        f2e4m3(0.25f * fmaxf(a0 - s0v - r0v, 0.f)) |
        (f2e4m3(0.25f * fmaxf(a1 - s1v - r1v, 0.f)) << 8));
}

// ---------------- classify (fp8 MFMA) + softmax ----------------
// A = [r0 | r1c | r2c] fp8 (scales 1, 1/2, 1/8) ; B = packed Wc fp8 (scales folded)
__global__ __launch_bounds__(256) void classify_mfma(const fp8_t* __restrict__ r0,
        const fp8_t* __restrict__ r1, const fp8_t* __restrict__ r2,
        const fp8_t* __restrict__ wcp, float* __restrict__ out) {
    const int t = threadIdx.x;
    const int l = t & 63, w = t >> 6;
    const int lm = l & 15, lg = l >> 4;
    const int base = blockIdx.x * 128 + w * 32;

    const int m0 = base + lm, m1 = base + 16 + lm;   // padded buffers: reads safe
    const fp8_t* p0_r0 = r0 + (size_t)m0 * 64  + lg * 8;
    const fp8_t* p0_r1 = r1 + (size_t)m0 * 128 + lg * 8;
    const fp8_t* p0_r2 = r2 + (size_t)m0 * 256 + lg * 8;
    const fp8_t* p1_r0 = r0 + (size_t)m1 * 64  + lg * 8;
    const fp8_t* p1_r1 = r1 + (size_t)m1 * 128 + lg * 8;
    const fp8_t* p1_r2 = r2 + (size_t)m1 * 256 + lg * 8;

    f32x4 acc[2][4];
#pragma unroll
    for (int i = 0; i < 2; ++i)
#pragma unroll
        for (int j = 0; j < 4; ++j) acc[i][j] = (f32x4){0.f, 0.f, 0.f, 0.f};

    auto aload = [&](const fp8_t* pr0, const fp8_t* pr1, const fp8_t* pr2, int kt) {
        const fp8_t* p = (kt < 64) ? (pr0 + kt) : (kt < 192) ? (pr1 + kt - 64) : (pr2 + kt - 192);
        return *(const i64*)p;
    };
    auto wb = [&](int ks, int nt) {
        return *(const i64*)(wcp + ((size_t)(ks * 4 + nt) * 64 + l) * 8);
    };

    const int NK = 14;  // 448/32
    i64 a0 = aload(p0_r0, p0_r1, p0_r2, 0);
    i64 a1 = aload(p1_r0, p1_r1, p1_r2, 0);
    i64 b0 = wb(0,0), b1 = wb(0,1), b2 = wb(0,2), b3 = wb(0,3);
    for (int ks = 0; ks < NK; ++ks) {
        i64 na0, na1, nb0, nb1, nb2, nb3;
        const bool more = (ks + 1 < NK);
        if (more) {
            int kt = (ks + 1) * 32;
            na0 = aload(p0_r0, p0_r1, p0_r2, kt);
            na1 = aload(p1_r0, p1_r1, p1_r2, kt);
            nb0 = wb(ks+1,0); nb1 = wb(ks+1,1); nb2 = wb(ks+1,2); nb3 = wb(ks+1,3);
        }
        acc[0][0] = MFMA_FP8(a0, b0, acc[0][0], 0, 0, 0);
        acc[1][0] = MFMA_FP8(a1, b0, acc[1][0], 0, 0, 0);
        acc[0][1] = MFMA_FP8(a0, b1, acc[0][1], 0, 0, 0);
        acc[1][1] = MFMA_FP8(a1, b1, acc[1][1], 0, 0, 0);
        acc[0][2] = MFMA_FP8(a0, b2, acc[0][2], 0, 0, 0);
        acc[1][2] = MFMA_FP8(a1, b2, acc[1][2], 0, 0, 0);
        acc[0][3] = MFMA_FP8(a0, b3, acc[0][3], 0, 0, 0);
        acc[1][3] = MFMA_FP8(a1, b3, acc[1][3], 0, 0, 0);
        if (more) { a0 = na0; a1 = na1; b0 = nb0; b1 = nb1; b2 = nb2; b3 = nb3; }
    }

#pragma unroll
    for (int rt = 0; rt < 2; ++rt)
#pragma unroll
        for (int r = 0; r < 4; ++r) {
            float v0 = acc[rt][0][r], v1 = acc[rt][1][r];
            float v2 = acc[rt][2][r], v3 = acc[rt][3][r];
            float m = fmaxf(fmaxf(v0, v1), fmaxf(v2, v3));
#pragma unroll
            for (int o = 1; o < 16; o <<= 1) m = fmaxf(m, __shfl_xor(m, o));
            float e0 = __expf(v0 - m), e1 = __expf(v1 - m);
            float e2 = __expf(v2 - m), e3 = __expf(v3 - m);
            float s = e0 + e1 + e2 + e3;
#pragma unroll
            for (int o = 1; o < 16; o <<= 1) s += __shfl_xor(s, o);
            float inv = 1.f / s;
            int R = base + rt * 16 + lg * 4 + r;
            if (R < N_NODES) {
                float* o = out + (size_t)R * 64 + lm;
                o[0]  = e0 * inv;
                o[16] = e1 * inv;
                o[32] = e2 * inv;
                o[48] = e3 * inv;
            }
        }
}

extern "C" void kernel_launch(void* const* d_in, const int* in_sizes, int n_in,
                              void* d_out, int out_size, void* d_ws, size_t ws_size,
                              hipStream_t stream) {
    const float* x    = (const float*)d_in[0];
    const int*   erow = (const int*)d_in[1];
    const int*   ecol = (const int*)d_in[2];
    const float* eval = (const float*)d_in[3];
    const float* we   = (const float*)d_in[4];
    const float* wc   = (const float*)d_in[5];
    float* out = (float*)d_out;

    char* wsp = (char*)d_ws;
    size_t off = 0;
    auto take = [&](size_t bytes) {
        char* p = wsp + off;
        off += (bytes + 255) & ~(size_t)255;
        return p;
    };
    fp8_t*  r0     = (fp8_t*)take((size_t)NPAD * 64);
    fp8_t*  sbuf   = (fp8_t*)take((size_t)NPAD * 128);  // s (64B rows) then s2' (128B rows)
    fp8_t*  r1c    = (fp8_t*)take((size_t)NPAD * 128);
    fp8_t*  r2c    = (fp8_t*)take((size_t)NPAD * 256);
    int*    cnt    = (int*)take((size_t)N_NODES * 4);
    int*    rowPtr = (int*)take((size_t)(N_NODES + 1) * 4);
    int*    fill   = (int*)take((size_t)N_NODES * 4);
    int*    bsum   = (int*)take((size_t)NB_SCAN * 4);
    uint2*  colval = (uint2*)take((size_t)NEDGE * 8);
    bf16_t* wep    = (bf16_t*)take((size_t)8  * 256 * 8 * 2);   // packed We (bf16)
    fp8_t*  wcp    = (fp8_t*)take((size_t)14 * 256 * 8);        // packed Wc (fp8)
    (void)ws_size; (void)in_sizes; (void)n_in; (void)out_size;

    hipMemsetAsync(cnt, 0, (size_t)N_NODES * 4, stream);

    prep_kernel<<<NB_EDGE + 8 + 14, 256, 0, stream>>>(erow, cnt, we, wep, wc, wcp);
    scan_a<<<NB_SCAN, 256, 0, stream>>>(cnt, bsum);
    scan_c<<<NB_SCAN, 256, 0, stream>>>(cnt, bsum, rowPtr, fill);
    scatter_embed_kernel<<<NB_EDGE + NB_GEMM, 256, 0, stream>>>(
        erow, ecol, eval, rowPtr, fill, colval, x, wep, r0);

    spmm64_kernel <<<12500, 256, 0, stream>>>(colval, rowPtr, r0, sbuf);
    spmm64f_kernel<<<12500, 256, 0, stream>>>(colval, rowPtr, sbuf, r0, r1c);
    spmm128_kernel<<<12500, 256, 0, stream>>>(colval, rowPtr, r1c, sbuf);
    spmm128f_kernel<<<12500, 256, 0, stream>>>(colval, rowPtr, sbuf, r1c, r2c);

    classify_mfma<<<NB_GEMM, 256, 0, stream>>>(r0, r1c, r2c, wcp, out);
}

// Round 13
// 271.478 us; speedup vs baseline: 1.1017x; 1.1017x over previous
//
#include <hip/hip_runtime.h>

#define N_NODES 50000
#define NPAD 50048            // padded row count (multiple of 128)
#define FEAT 256
#define HID 64
#define NEDGE 800000
#define SCAN_CHUNK 2048
#define NB_SCAN 25            // ceil(50000/2048)
#define NB_EDGE 3125          // NEDGE/256
#define NB_GEMM 391           // NPAD/128

typedef unsigned short bf16_t;
typedef __attribute__((ext_vector_type(8))) short bf16x8;   // 8 bf16 = 4 VGPR
typedef __attribute__((ext_vector_type(4))) float f32x4;

#define MFMA_BF16 __builtin_amdgcn_mfma_f32_16x16x32_bf16

__device__ __forceinline__ bf16_t f2bf(float f) {
    union { float f; unsigned u; } v; v.f = f;
    unsigned r = v.u + 0x7fff + ((v.u >> 16) & 1);   // RNE
    return (bf16_t)(r >> 16);
}
__device__ __forceinline__ void unpack2(unsigned u, float& lo, float& hi) {
    union { unsigned u; float f; } a, b;
    a.u = u << 16; b.u = u & 0xffff0000u;
    lo = a.f; hi = b.f;
}
__device__ __forceinline__ unsigned pack2(float lo, float hi) {
    return ((unsigned)f2bf(lo)) | (((unsigned)f2bf(hi)) << 16);
}

// ---------------- fused prep: hist (blocks 0..3124) ∥ pack_we (8) ∥ pack_wc (14) ----------------
__device__ __forceinline__ void pack_w_body(const float* __restrict__ wsrc,
        bf16_t* __restrict__ wdst, int idx) {
    int lane = idx & 63, nt = (idx >> 6) & 3, ks = idx >> 8;
    int kb  = ks * 32 + ((lane >> 4) * 8);
    int col = nt * 16 + (lane & 15);
    unsigned p[4];
#pragma unroll
    for (int j = 0; j < 4; ++j)
        p[j] = pack2(wsrc[(size_t)(kb + 2*j) * 64 + col],
                     wsrc[(size_t)(kb + 2*j + 1) * 64 + col]);
    uint4 u; u.x = p[0]; u.y = p[1]; u.z = p[2]; u.w = p[3];
    *(uint4*)(wdst + (size_t)idx * 8) = u;
}

__global__ __launch_bounds__(256) void prep_kernel(const int* __restrict__ rows,
        int* __restrict__ cnt, const float* __restrict__ we, bf16_t* __restrict__ wep,
        const float* __restrict__ wc, bf16_t* __restrict__ wcp) {
    const int b = blockIdx.x, t = threadIdx.x;
    if (b < NB_EDGE) {
        int e = b * 256 + t;
        if (e < NEDGE) atomicAdd(&cnt[rows[e]], 1);
    } else if (b < NB_EDGE + 8) {
        pack_w_body(we, wep, (b - NB_EDGE) * 256 + t);
    } else {
        pack_w_body(wc, wcp, (b - NB_EDGE - 8) * 256 + t);
    }
}

// ---------------- scans ----------------
__global__ __launch_bounds__(256) void scan_a(const int* __restrict__ cnt,
        int* __restrict__ bsum) {
    __shared__ int sd[256];
    const int t = threadIdx.x;
    const int base = blockIdx.x * SCAN_CHUNK + t * 8;
    int s = 0;
#pragma unroll
    for (int i = 0; i < 8; ++i) {
        int idx = base + i;
        s += (idx < N_NODES) ? cnt[idx] : 0;
    }
    sd[t] = s; __syncthreads();
    for (int off = 128; off > 0; off >>= 1) {
        if (t < off) sd[t] += sd[t + off];
        __syncthreads();
    }
    if (t == 0) bsum[blockIdx.x] = sd[0];
}

__global__ __launch_bounds__(256) void scan_c(const int* __restrict__ cnt,
        const int* __restrict__ bsum, int* __restrict__ rowPtr,
        int* __restrict__ fill) {
    __shared__ int sd[256];
    __shared__ int sboff;
    const int t = threadIdx.x;
    const int base = blockIdx.x * SCAN_CHUNK + t * 8;
    if (t == 0) {
        int a = 0, tot = 0;
        for (int b = 0; b < NB_SCAN; ++b) {
            int v = bsum[b];
            if (b < (int)blockIdx.x) a += v;
            tot += v;
        }
        sboff = a;
        if (blockIdx.x == NB_SCAN - 1) rowPtr[N_NODES] = tot;
    }
    int v[8];
    int s = 0;
#pragma unroll
    for (int i = 0; i < 8; ++i) {
        int idx = base + i;
        v[i] = (idx < N_NODES) ? cnt[idx] : 0;
        s += v[i];
    }
    sd[t] = s; __syncthreads();
    for (int off = 1; off < 256; off <<= 1) {
        int add = (t >= off) ? sd[t - off] : 0;
        __syncthreads();
        sd[t] += add;
        __syncthreads();
    }
    int run = sboff + (sd[t] - s);
#pragma unroll
    for (int i = 0; i < 8; ++i) {
        int idx = base + i;
        if (idx < N_NODES) { rowPtr[idx] = run; fill[idx] = 0; }
        run += v[i];
    }
}

// ---------------- fused scatter (blocks 0..3124) ∥ embed_mfma (blocks 3125..3515) ----------------
__global__ __launch_bounds__(256) void scatter_embed_kernel(
        const int* __restrict__ rows, const int* __restrict__ cols,
        const float* __restrict__ vals, const int* __restrict__ rowPtr,
        int* __restrict__ fill, uint2* __restrict__ colval,
        const float* __restrict__ x, const bf16_t* __restrict__ wep,
        bf16_t* __restrict__ r0) {
    if (blockIdx.x < NB_EDGE) {
        int e = blockIdx.x * 256 + threadIdx.x;
        if (e < NEDGE) {
            int r = rows[e];
            int p = rowPtr[r] + atomicAdd(&fill[r], 1);
            uint2 cv; cv.x = (unsigned)cols[e]; cv.y = __float_as_uint(vals[e]);
            colval[p] = cv;
        }
        return;
    }
    // ---- embed body ----
    const int blk = blockIdx.x - NB_EDGE;
    const int t = threadIdx.x;
    const int l = t & 63, w = t >> 6;
    const int lm = l & 15, lg = l >> 4;
    const int base = blk * 128 + w * 32;

    int m0 = base + lm, m1 = base + 16 + lm;
    if (m0 >= N_NODES) m0 = N_NODES - 1;
    if (m1 >= N_NODES) m1 = N_NODES - 1;
    const float* xp0 = x + (size_t)m0 * FEAT + lg * 8;
    const float* xp1 = x + (size_t)m1 * FEAT + lg * 8;

    f32x4 acc[2][4];
#pragma unroll
    for (int i = 0; i < 2; ++i)
#pragma unroll
        for (int j = 0; j < 4; ++j) acc[i][j] = (f32x4){0.f, 0.f, 0.f, 0.f};

    auto aload = [&](const float* p) {
        float4 u0 = *(const float4*)(p);
        float4 u1 = *(const float4*)(p + 4);
        bf16x8 r;
        r[0] = (short)f2bf(u0.x); r[1] = (short)f2bf(u0.y);
        r[2] = (short)f2bf(u0.z); r[3] = (short)f2bf(u0.w);
        r[4] = (short)f2bf(u1.x); r[5] = (short)f2bf(u1.y);
        r[6] = (short)f2bf(u1.z); r[7] = (short)f2bf(u1.w);
        return r;
    };
    auto wb = [&](int ks, int nt) {
        return *(const bf16x8*)(wep + ((size_t)(ks * 4 + nt) * 64 + l) * 8);
    };

    const int NK = FEAT / 32;  // 8
    bf16x8 a0 = aload(xp0), a1 = aload(xp1);
    bf16x8 b0 = wb(0,0), b1 = wb(0,1), b2 = wb(0,2), b3 = wb(0,3);
    for (int ks = 0; ks < NK; ++ks) {
        bf16x8 na0, na1, nb0, nb1, nb2, nb3;
        const bool more = (ks + 1 < NK);
        if (more) {
            int kt = (ks + 1) * 32;
            na0 = aload(xp0 + kt); na1 = aload(xp1 + kt);
            nb0 = wb(ks+1,0); nb1 = wb(ks+1,1); nb2 = wb(ks+1,2); nb3 = wb(ks+1,3);
        }
        acc[0][0] = MFMA_BF16(a0, b0, acc[0][0], 0, 0, 0);
        acc[1][0] = MFMA_BF16(a1, b0, acc[1][0], 0, 0, 0);
        acc[0][1] = MFMA_BF16(a0, b1, acc[0][1], 0, 0, 0);
        acc[1][1] = MFMA_BF16(a1, b1, acc[1][1], 0, 0, 0);
        acc[0][2] = MFMA_BF16(a0, b2, acc[0][2], 0, 0, 0);
        acc[1][2] = MFMA_BF16(a1, b2, acc[1][2], 0, 0, 0);
        acc[0][3] = MFMA_BF16(a0, b3, acc[0][3], 0, 0, 0);
        acc[1][3] = MFMA_BF16(a1, b3, acc[1][3], 0, 0, 0);
        if (more) { a0 = na0; a1 = na1; b0 = nb0; b1 = nb1; b2 = nb2; b3 = nb3; }
    }

#pragma unroll
    for (int rt = 0; rt < 2; ++rt)
#pragma unroll
        for (int r = 0; r < 4; ++r) {
            int R = base + rt * 16 + lg * 4 + r;
            if (R < N_NODES) {
                bf16_t* o = r0 + (size_t)R * HID + lm;
                o[0]  = f2bf(fmaxf(acc[rt][0][r], 0.f));
                o[16] = f2bf(fmaxf(acc[rt][1][r], 0.f));
                o[32] = f2bf(fmaxf(acc[rt][2][r], 0.f));
                o[48] = f2bf(fmaxf(acc[rt][3][r], 0.f));
            }
        }
}

// ---------------- SpMM w64: pair-lane (2 edges / gather instr, 16 edges / batch) ----------------
__global__ __launch_bounds__(256) void spmm64_kernel(const uint2* __restrict__ colval,
        const int* __restrict__ rowPtr,
        const bf16_t* __restrict__ src, bf16_t* __restrict__ dst) {
    const int l = threadIdx.x & 63;
    const int c = l & 31, h = l >> 5;           // c = uint feature-pair, h = edge parity
    const int row  = (int)((blockIdx.x * 256u + threadIdx.x) >> 6);
    const int beg = rowPtr[row], end = rowPtr[row + 1];
    const unsigned* srcu = (const unsigned*)src;  // row stride 32 uints
    float a0 = 0.f, a1 = 0.f;
    int i = beg;
    for (; i + 16 <= end; i += 16) {
        uint2 cv[8]; unsigned g[8];
#pragma unroll
        for (int j = 0; j < 8; ++j) cv[j] = colval[i + 2*j + h];
#pragma unroll
        for (int j = 0; j < 8; ++j) g[j] = srcu[(size_t)cv[j].x * 32 + c];
#pragma unroll
        for (int j = 0; j < 8; ++j) {
            float lo, hi; unpack2(g[j], lo, hi);
            float v = __uint_as_float(cv[j].y);
            a0 += v*lo; a1 += v*hi;
        }
    }
    for (; i + 2 <= end; i += 2) {
        uint2 cv = colval[i + h];
        float lo, hi; unpack2(srcu[(size_t)cv.x*32 + c], lo, hi);
        float v = __uint_as_float(cv.y);
        a0 += v*lo; a1 += v*hi;
    }
    if (i + h < end) {   // odd leftover edge: h==0 half only
        uint2 cv = colval[i + h];
        float lo, hi; unpack2(srcu[(size_t)cv.x*32 + c], lo, hi);
        float v = __uint_as_float(cv.y);
        a0 += v*lo; a1 += v*hi;
    }
    a0 += __shfl_xor(a0, 32);
    a1 += __shfl_xor(a1, 32);
    if (h == 0)
        ((unsigned*)dst)[(size_t)row*32 + c] = pack2(a0, a1);
}

// t = adj@s fused with r1cat = relu(concat[s-r0, t-s-r0])
__global__ __launch_bounds__(256) void spmm64f_kernel(const uint2* __restrict__ colval,
        const int* __restrict__ rowPtr,
        const bf16_t* __restrict__ s, const bf16_t* __restrict__ r0,
        bf16_t* __restrict__ r1c) {
    const int l = threadIdx.x & 63;
    const int c = l & 31, h = l >> 5;
    const int row  = (int)((blockIdx.x * 256u + threadIdx.x) >> 6);
    const int beg = rowPtr[row], end = rowPtr[row + 1];
    const unsigned* su = (const unsigned*)s;      // row stride 32 uints
    const unsigned* r0u = (const unsigned*)r0;
    float a0 = 0.f, a1 = 0.f;
    int i = beg;
    for (; i + 16 <= end; i += 16) {
        uint2 cv[8]; unsigned g[8];
#pragma unroll
        for (int j = 0; j < 8; ++j) cv[j] = colval[i + 2*j + h];
#pragma unroll
        for (int j = 0; j < 8; ++j) g[j] = su[(size_t)cv[j].x * 32 + c];
#pragma unroll
        for (int j = 0; j < 8; ++j) {
            float lo, hi; unpack2(g[j], lo, hi);
            float v = __uint_as_float(cv[j].y);
            a0 += v*lo; a1 += v*hi;
        }
    }
    for (; i + 2 <= end; i += 2) {
        uint2 cv = colval[i + h];
        float lo, hi; unpack2(su[(size_t)cv.x*32 + c], lo, hi);
        float v = __uint_as_float(cv.y);
        a0 += v*lo; a1 += v*hi;
    }
    if (i + h < end) {
        uint2 cv = colval[i + h];
        float lo, hi; unpack2(su[(size_t)cv.x*32 + c], lo, hi);
        float v = __uint_as_float(cv.y);
        a0 += v*lo; a1 += v*hi;
    }
    a0 += __shfl_xor(a0, 32);
    a1 += __shfl_xor(a1, 32);
    if (h == 0) {
        float sv0, sv1, rv0, rv1;
        unpack2(su[(size_t)row*32 + c], sv0, sv1);
        unpack2(r0u[(size_t)row*32 + c], rv0, rv1);
        unsigned* r1u = (unsigned*)r1c;  // row stride 64 uints
        r1u[(size_t)row*64 + c]      = pack2(fmaxf(sv0 - rv0, 0.f), fmaxf(sv1 - rv1, 0.f));
        r1u[(size_t)row*64 + 32 + c] = pack2(fmaxf(a0 - sv0 - rv0, 0.f), fmaxf(a1 - sv1 - rv1, 0.f));
    }
}

// ---------------- SpMM w128: lane-per-edge uint, batch deepened to 8 ----------------
__global__ __launch_bounds__(256) void spmm128_kernel(const uint2* __restrict__ colval,
        const int* __restrict__ rowPtr,
        const bf16_t* __restrict__ src, bf16_t* __restrict__ dst) {
    const int lane = threadIdx.x & 63;
    const int row  = (int)((blockIdx.x * 256u + threadIdx.x) >> 6);
    const int beg = rowPtr[row], end = rowPtr[row + 1];
    const unsigned* srcu = (const unsigned*)src;  // row stride 64 uints
    float a0 = 0.f, a1 = 0.f;
    int i = beg;
    for (; i + 8 <= end; i += 8) {
        uint2 cv[8]; unsigned u[8];
#pragma unroll
        for (int j = 0; j < 8; ++j) cv[j] = colval[i+j];
#pragma unroll
        for (int j = 0; j < 8; ++j) u[j] = srcu[(size_t)cv[j].x*64 + lane];
#pragma unroll
        for (int j = 0; j < 8; ++j) {
            float lo, hi; unpack2(u[j], lo, hi);
            float v = __uint_as_float(cv[j].y);
            a0 += v*lo; a1 += v*hi;
        }
    }
    for (; i < end; ++i) {
        uint2 cv = colval[i];
        float lo, hi; unpack2(srcu[(size_t)cv.x*64 + lane], lo, hi);
        float v = __uint_as_float(cv.y);
        a0 += v*lo; a1 += v*hi;
    }
    ((unsigned*)dst)[(size_t)row*64 + lane] = pack2(a0, a1);
}

__global__ __launch_bounds__(256) void spmm128f_kernel(const uint2* __restrict__ colval,
        const int* __restrict__ rowPtr,
        const bf16_t* __restrict__ s2, const bf16_t* __restrict__ r1,
        bf16_t* __restrict__ r2c) {
    const int lane = threadIdx.x & 63;
    const int row  = (int)((blockIdx.x * 256u + threadIdx.x) >> 6);
    const int beg = rowPtr[row], end = rowPtr[row + 1];
    const unsigned* s2u = (const unsigned*)s2;
    const unsigned* r1u = (const unsigned*)r1;
    float a0 = 0.f, a1 = 0.f;
    int i = beg;
    for (; i + 8 <= end; i += 8) {
        uint2 cv[8]; unsigned u[8];
#pragma unroll
        for (int j = 0; j < 8; ++j) cv[j] = colval[i+j];
#pragma unroll
        for (int j = 0; j < 8; ++j) u[j] = s2u[(size_t)cv[j].x*64 + lane];
#pragma unroll
        for (int j = 0; j < 8; ++j) {
            float lo, hi; unpack2(u[j], lo, hi);
            float v = __uint_as_float(cv[j].y);
            a0 += v*lo; a1 += v*hi;
        }
    }
    for (; i < end; ++i) {
        uint2 cv = colval[i];
        float lo, hi; unpack2(s2u[(size_t)cv.x*64 + lane], lo, hi);
        float v = __uint_as_float(cv.y);
        a0 += v*lo; a1 += v*hi;
    }
    float s0v, s1v, r0v, r1v;
    unpack2(s2u[(size_t)row*64 + lane], s0v, s1v);
    unpack2(r1u[(size_t)row*64 + lane], r0v, r1v);
    unsigned* r2u = (unsigned*)r2c;  // row stride 128 uints
    r2u[(size_t)row*128 + lane]      = pack2(fmaxf(s0v - r0v, 0.f), fmaxf(s1v - r1v, 0.f));
    r2u[(size_t)row*128 + 64 + lane] = pack2(fmaxf(a0 - s0v - r0v, 0.f), fmaxf(a1 - s1v - r1v, 0.f));
}

// ---------------- classify (MFMA) + softmax ----------------
__global__ __launch_bounds__(256) void classify_mfma(const bf16_t* __restrict__ r0,
        const bf16_t* __restrict__ r1, const bf16_t* __restrict__ r2,
        const bf16_t* __restrict__ wcp, float* __restrict__ out) {
    const int t = threadIdx.x;
    const int l = t & 63, w = t >> 6;
    const int lm = l & 15, lg = l >> 4;
    const int base = blockIdx.x * 128 + w * 32;

    const int m0 = base + lm, m1 = base + 16 + lm;   // padded buffers: reads safe
    const bf16_t* p0_r0 = r0 + (size_t)m0 * 64  + lg * 8;
    const bf16_t* p0_r1 = r1 + (size_t)m0 * 128 + lg * 8;
    const bf16_t* p0_r2 = r2 + (size_t)m0 * 256 + lg * 8;
    const bf16_t* p1_r0 = r0 + (size_t)m1 * 64  + lg * 8;
    const bf16_t* p1_r1 = r1 + (size_t)m1 * 128 + lg * 8;
    const bf16_t* p1_r2 = r2 + (size_t)m1 * 256 + lg * 8;

    f32x4 acc[2][4];
#pragma unroll
    for (int i = 0; i < 2; ++i)
#pragma unroll
        for (int j = 0; j < 4; ++j) acc[i][j] = (f32x4){0.f, 0.f, 0.f, 0.f};

    auto aload = [&](const bf16_t* pr0, const bf16_t* pr1, const bf16_t* pr2, int kt) {
        const bf16_t* p = (kt < 64) ? (pr0 + kt) : (kt < 192) ? (pr1 + kt - 64) : (pr2 + kt - 192);
        return *(const bf16x8*)p;
    };
    auto wb = [&](int ks, int nt) {
        return *(const bf16x8*)(wcp + ((size_t)(ks * 4 + nt) * 64 + l) * 8);
    };

    const int NK = 14;  // 448/32
    bf16x8 a0 = aload(p0_r0, p0_r1, p0_r2, 0);
    bf16x8 a1 = aload(p1_r0, p1_r1, p1_r2, 0);
    bf16x8 b0 = wb(0,0), b1 = wb(0,1), b2 = wb(0,2), b3 = wb(0,3);
    for (int ks = 0; ks < NK; ++ks) {
        bf16x8 na0, na1, nb0, nb1, nb2, nb3;
        const bool more = (ks + 1 < NK);
        if (more) {
            int kt = (ks + 1) * 32;
            na0 = aload(p0_r0, p0_r1, p0_r2, kt);
            na1 = aload(p1_r0, p1_r1, p1_r2, kt);
            nb0 = wb(ks+1,0); nb1 = wb(ks+1,1); nb2 = wb(ks+1,2); nb3 = wb(ks+1,3);
        }
        acc[0][0] = MFMA_BF16(a0, b0, acc[0][0], 0, 0, 0);
        acc[1][0] = MFMA_BF16(a1, b0, acc[1][0], 0, 0, 0);
        acc[0][1] = MFMA_BF16(a0, b1, acc[0][1], 0, 0, 0);
        acc[1][1] = MFMA_BF16(a1, b1, acc[1][1], 0, 0, 0);
        acc[0][2] = MFMA_BF16(a0, b2, acc[0][2], 0, 0, 0);
        acc[1][2] = MFMA_BF16(a1, b2, acc[1][2], 0, 0, 0);
        acc[0][3] = MFMA_BF16(a0, b3, acc[0][3], 0, 0, 0);
        acc[1][3] = MFMA_BF16(a1, b3, acc[1][3], 0, 0, 0);
        if (more) { a0 = na0; a1 = na1; b0 = nb0; b1 = nb1; b2 = nb2; b3 = nb3; }
    }

#pragma unroll
    for (int rt = 0; rt < 2; ++rt)
#pragma unroll
        for (int r = 0; r < 4; ++r) {
            float v0 = acc[rt][0][r], v1 = acc[rt][1][r];
            float v2 = acc[rt][2][r], v3 = acc[rt][3][r];
            float m = fmaxf(fmaxf(v0, v1), fmaxf(v2, v3));
#pragma unroll
            for (int o = 1; o < 16; o <<= 1) m = fmaxf(m, __shfl_xor(m, o));
            float e0 = __expf(v0 - m), e1 = __expf(v1 - m);
            float e2 = __expf(v2 - m), e3 = __expf(v3 - m);
            float s = e0 + e1 + e2 + e3;
#pragma unroll
            for (int o = 1; o < 16; o <<= 1) s += __shfl_xor(s, o);
            float inv = 1.f / s;
            int R = base + rt * 16 + lg * 4 + r;
            if (R < N_NODES) {
                float* o = out + (size_t)R * 64 + lm;
                o[0]  = e0 * inv;
                o[16] = e1 * inv;
                o[32] = e2 * inv;
                o[48] = e3 * inv;
            }
        }
}

extern "C" void kernel_launch(void* const* d_in, const int* in_sizes, int n_in,
                              void* d_out, int out_size, void* d_ws, size_t ws_size,
                              hipStream_t stream) {
    const float* x    = (const float*)d_in[0];
    const int*   erow = (const int*)d_in[1];
    const int*   ecol = (const int*)d_in[2];
    const float* eval = (const float*)d_in[3];
    const float* we   = (const float*)d_in[4];
    const float* wc   = (const float*)d_in[5];
    float* out = (float*)d_out;

    char* wsp = (char*)d_ws;
    size_t off = 0;
    auto take = [&](size_t bytes) {
        char* p = wsp + off;
        off += (bytes + 255) & ~(size_t)255;
        return p;
    };
    bf16_t* r0     = (bf16_t*)take((size_t)NPAD * 64 * 2);
    bf16_t* sbuf   = (bf16_t*)take((size_t)NPAD * 128 * 2);  // s (w64) then s2 (w128)
    bf16_t* r1c    = (bf16_t*)take((size_t)NPAD * 128 * 2);
    bf16_t* r2c    = (bf16_t*)take((size_t)NPAD * 256 * 2);
    int*    cnt    = (int*)take((size_t)N_NODES * 4);
    int*    rowPtr = (int*)take((size_t)(N_NODES + 1) * 4);
    int*    fill   = (int*)take((size_t)N_NODES * 4);
    int*    bsum   = (int*)take((size_t)NB_SCAN * 4);
    uint2*  colval = (uint2*)take((size_t)NEDGE * 8);
    bf16_t* wep    = (bf16_t*)take((size_t)8  * 256 * 8 * 2);   // 8 ksteps packed We
    bf16_t* wcp    = (bf16_t*)take((size_t)14 * 256 * 8 * 2);   // 14 ksteps packed Wc
    (void)ws_size; (void)in_sizes; (void)n_in; (void)out_size;

    hipMemsetAsync(cnt, 0, (size_t)N_NODES * 4, stream);

    // hist ∥ pack_we ∥ pack_wc
    prep_kernel<<<NB_EDGE + 8 + 14, 256, 0, stream>>>(erow, cnt, we, wep, wc, wcp);
    scan_a<<<NB_SCAN, 256, 0, stream>>>(cnt, bsum);
    scan_c<<<NB_SCAN, 256, 0, stream>>>(cnt, bsum, rowPtr, fill);   // also zeroes fill
    // scatter ∥ embed
    scatter_embed_kernel<<<NB_EDGE + NB_GEMM, 256, 0, stream>>>(
        erow, ecol, eval, rowPtr, fill, colval, x, wep, r0);

    spmm64_kernel <<<12500, 256, 0, stream>>>(colval, rowPtr, r0, sbuf);
    spmm64f_kernel<<<12500, 256, 0, stream>>>(colval, rowPtr, sbuf, r0, r1c);
    spmm128_kernel<<<12500, 256, 0, stream>>>(colval, rowPtr, r1c, sbuf);
    spmm128f_kernel<<<12500, 256, 0, stream>>>(colval, rowPtr, sbuf, r1c, r2c);

    classify_mfma<<<NB_GEMM, 256, 0, stream>>>(r0, r1c, r2c, wcp, out);
}